// Round 2
// baseline (109.334 us; speedup 1.0000x reference)
//
#include <hip/hip_runtime.h>

// RankingLoss: loss = sum_{i,j} [c_i==0 && Y_j>Y_i] * relu(risk_j - risk_i) / count
// risk = sum(hazards[:, :4], axis=1). B = 8192, N_CLASSES = 4, MARGIN = 0.
//
// R5 design: ONE worker kernel + 4-byte memset (cooperative launch crashed the
// harness in R4 — grid.sync() not graph-capture-safe here).
//  rl_fused (grid 32 j-tiles x 32 i-chunks, 256 thr): each block class-compacts
//    its own 256-wide i-chunk in LDS (ballot + LDS-atomic, uncensored & Y<3,
//    padded to 64 with +1e30 sentinels), then pure-VALU pair loop: per class
//    group, d = rjc - ri; acc += max(d,0); ri = dpp wave_ror:1 (4 instr / 64
//    pairs, no LDS/SALU in loop). Exact pair count per block from class
//    histograms. Partials -> ws with release/agent atomics, then a ticket
//    atomicAdd on a memset-zeroed counter; the LAST block (ticket==NBLK-1)
//    reduces the 1024 partials and writes out. No spin, no co-residency
//    assumption, deadlock-free under any scheduling.
// Fixed harness floor: 268MB ws re-poison fill ~40us/iter dominates total.

#define B_SIZE 8192
#define BLOCK  256
#define JT     (B_SIZE / BLOCK)      // 32 j-tiles
#define IC     (B_SIZE / BLOCK)      // 32 i-chunks
#define NBLK   (JT * IC)             // 1024 partials
#define CAP    128                   // per-class capacity within a 256-chunk (mean 32, 17 sigma)

__global__ __launch_bounds__(BLOCK) void rl_fused(
    const float4* __restrict__ hz,   // hazards [B] as float4 rows
    const int*    __restrict__ Y,
    const int*    __restrict__ c,
    float*        __restrict__ psum,
    int*          __restrict__ pcnt,
    int*          __restrict__ dcnt, // ticket counter, memset to 0 pre-launch
    float*        __restrict__ out)
{
    __shared__ float sPad[3 * CAP];  // class-bucketed risks, sentinel-padded
    __shared__ int   sCnt[3];        // per-class uncensored count in this i-chunk
    __shared__ int   sSuf[3];        // #{j in tile: yj > a}
    __shared__ float sA[BLOCK / 64];
    __shared__ int   sN[BLOCK / 64];
    __shared__ int   sLast;

    const int tid  = threadIdx.x;
    const int lane = tid & 63;
    const int wave = tid >> 6;

    if (tid < 3) { sCnt[tid] = 0; sSuf[tid] = 0; }
    for (int k = tid; k < 3 * CAP; k += BLOCK) sPad[k] = 1e30f;

    // ---- j side: this thread's own column ----
    const int j = blockIdx.x * BLOCK + tid;
    const float4 hj = hz[j];
    const float rj = (hj.x + hj.y) + (hj.z + hj.w);
    const int   yj = Y[j];

    // ---- i side: this thread's own row in the block's i-chunk ----
    const int i = blockIdx.y * BLOCK + tid;
    const float4 hi = hz[i];
    const float ri0 = (hi.x + hi.y) + (hi.z + hi.w);
    const int   yi = Y[i];
    const bool  keep = (c[i] == 0);

    __syncthreads();   // sentinel fill + counter init visible

    // ---- compact i-chunk into class buckets; j suffix histogram ----
    #pragma unroll
    for (int cls = 0; cls < 3; ++cls) {
        const bool mine = keep && (yi == cls);
        const unsigned long long m = __ballot(mine);
        if (m) {                                     // wave-uniform
            const int pop  = (int)__popcll(m);
            const int rank = (int)__popcll(m & ((1ull << lane) - 1ull));
            int base;
            if (lane == 0) base = atomicAdd(&sCnt[cls], pop);
            base = __shfl(base, 0, 64);
            const int slot = base + rank;
            if (mine && slot < CAP) sPad[cls * CAP + slot] = ri0;
        }
        const unsigned long long mj = __ballot(yj > cls);
        if (lane == 0 && mj) atomicAdd(&sSuf[cls], (int)__popcll(mj));
    }
    __syncthreads();

    const float rj0 = (yj > 0) ? rj : -1e30f;
    const float rj1 = (yj > 1) ? rj : -1e30f;
    const float rj2 = (yj > 2) ? rj : -1e30f;

    // ---- pure-VALU pair loop: 4 instr per 64 pairs ----
    float acc = 0.0f;
    #pragma unroll
    for (int cls = 0; cls < 3; ++cls) {
        const float rjc = (cls == 0) ? rj0 : (cls == 1) ? rj1 : rj2;
        const int n = min(sCnt[cls], CAP);
        for (int g = 0; g * 64 < n; ++g) {           // uniform trip count
            float ri = sPad[cls * CAP + g * 64 + lane];
            #pragma unroll
            for (int it = 0; it < 64; ++it) {
                acc += fmaxf(rjc - ri, 0.0f);        // sentinels kill masked terms
                ri = __uint_as_float((unsigned)__builtin_amdgcn_mov_dpp(
                         (int)__float_as_uint(ri), 0x13C /*wave_ror:1*/, 0xF, 0xF, true));
            }
        }
    }

    // ---- block reduction -> one partial (sum + exact count) per block ----
    #pragma unroll
    for (int off = 32; off > 0; off >>= 1) acc += __shfl_down(acc, off, 64);
    if (lane == 0) sA[wave] = acc;
    __syncthreads();
    if (tid == 0) {
        const int gid = blockIdx.y * JT + blockIdx.x;
        const float blockSum = (sA[0] + sA[1]) + (sA[2] + sA[3]);
        const int   blockCnt = sCnt[0] * sSuf[0] + sCnt[1] * sSuf[1] + sCnt[2] * sSuf[2];
        __hip_atomic_store(&psum[gid], blockSum, __ATOMIC_RELEASE, __HIP_MEMORY_SCOPE_AGENT);
        __hip_atomic_store(&pcnt[gid], blockCnt, __ATOMIC_RELEASE, __HIP_MEMORY_SCOPE_AGENT);
        __threadfence();                             // device-scope: partials visible
        const int ticket = __hip_atomic_fetch_add(dcnt, 1, __ATOMIC_ACQ_REL,
                                                  __HIP_MEMORY_SCOPE_AGENT);
        sLast = (ticket == NBLK - 1) ? 1 : 0;
    }
    __syncthreads();

    // ---- last-arriving block reduces the 1024 partials (no spin) ----
    if (sLast) {
        __threadfence();                             // pair with releases above
        float a = 0.0f; int n = 0;
        #pragma unroll
        for (int k = 0; k < NBLK / BLOCK; ++k) {
            a += __hip_atomic_load(&psum[k * BLOCK + tid], __ATOMIC_RELAXED,
                                   __HIP_MEMORY_SCOPE_AGENT);
            n += __hip_atomic_load(&pcnt[k * BLOCK + tid], __ATOMIC_RELAXED,
                                   __HIP_MEMORY_SCOPE_AGENT);
        }
        #pragma unroll
        for (int off = 32; off > 0; off >>= 1) {
            a += __shfl_down(a, off, 64);
            n += __shfl_down(n, off, 64);
        }
        if (lane == 0) { sA[wave] = a; sN[wave] = n; }
        __syncthreads();
        if (tid == 0) {
            const float A = (sA[0] + sA[1]) + (sA[2] + sA[3]);
            const int   N = (sN[0] + sN[1]) + (sN[2] + sN[3]);
            out[0] = (N > 0) ? (A / (float)N) : 0.0f;
        }
    }
}

extern "C" void kernel_launch(void* const* d_in, const int* in_sizes, int n_in,
                              void* d_out, int out_size, void* d_ws, size_t ws_size,
                              hipStream_t stream) {
    const float4* hz = (const float4*)d_in[0];  // hazards [8192 x 4] f32
    // d_in[1] = S, unused by the reference computation.
    const int* Y = (const int*)d_in[2];
    const int* c = (const int*)d_in[3];

    float* psum = (float*)d_ws;                 // [1024] f32
    int*   pcnt = (int*)d_ws + NBLK;            // [1024] i32
    int*   dcnt = (int*)d_ws + 2 * NBLK;        // [1] ticket counter
    float* out  = (float*)d_out;

    hipMemsetAsync(dcnt, 0, sizeof(int), stream);
    rl_fused<<<dim3(JT, IC), BLOCK, 0, stream>>>(hz, Y, c, psum, pcnt, dcnt, out);
}

// Round 3
// 75.224 us; speedup vs baseline: 1.4534x; 1.4534x over previous
//
#include <hip/hip_runtime.h>

// RankingLoss: loss = sum_{i,j} [c_i==0 && Y_j>Y_i] * relu(risk_j - risk_i) / count
// risk = sum(hazards[:, :4], axis=1). B = 8192, N_CLASSES = 4, MARGIN = 0.
//
// R6 design: ONE worker kernel + 4-byte memset, RELAXED-ONLY atomics.
//  R5 lesson: agent-scope release/acquire/threadfence emit buffer_wbl2 /
//  buffer_inv on gfx950 (per-XCD L2 non-coherent). With the harness's 268MB
//  poison fill leaving L2 full of dirty lines, 1024 blocks x wbl2 = 55us
//  cache-maintenance storm (kernel was 60us @ 9% VALU, 0.2% HBM).
//  Fix: relaxed atomic stores to psum/pcnt (coherent-point path, no cache
//  maintenance), explicit wave-local `s_waitcnt vmcnt(0)`, relaxed ticket
//  fetch_add; last-arriving block (ticket==NBLK-1) reduces 1024 partials via
//  relaxed atomic loads in fixed order (deterministic sum). No spin,
//  deadlock-free under any scheduling.
// Fixed harness floor: 268MB ws re-poison fill ~40us/iter dominates total.

#define B_SIZE 8192
#define BLOCK  256
#define JT     (B_SIZE / BLOCK)      // 32 j-tiles
#define IC     (B_SIZE / BLOCK)      // 32 i-chunks
#define NBLK   (JT * IC)             // 1024 partials
#define CAP    128                   // per-class capacity within a 256-chunk (mean 32, 17 sigma)

__global__ __launch_bounds__(BLOCK) void rl_fused(
    const float4* __restrict__ hz,   // hazards [B] as float4 rows
    const int*    __restrict__ Y,
    const int*    __restrict__ c,
    float*        __restrict__ psum,
    int*          __restrict__ pcnt,
    int*          __restrict__ dcnt, // ticket counter, memset to 0 pre-launch
    float*        __restrict__ out)
{
    __shared__ float sPad[3 * CAP];  // class-bucketed risks, sentinel-padded
    __shared__ int   sCnt[3];        // per-class uncensored count in this i-chunk
    __shared__ int   sSuf[3];        // #{j in tile: yj > a}
    __shared__ float sA[BLOCK / 64];
    __shared__ int   sN[BLOCK / 64];
    __shared__ int   sLast;

    const int tid  = threadIdx.x;
    const int lane = tid & 63;
    const int wave = tid >> 6;

    if (tid < 3) { sCnt[tid] = 0; sSuf[tid] = 0; }
    for (int k = tid; k < 3 * CAP; k += BLOCK) sPad[k] = 1e30f;

    // ---- j side: this thread's own column ----
    const int j = blockIdx.x * BLOCK + tid;
    const float4 hj = hz[j];
    const float rj = (hj.x + hj.y) + (hj.z + hj.w);
    const int   yj = Y[j];

    // ---- i side: this thread's own row in the block's i-chunk ----
    const int i = blockIdx.y * BLOCK + tid;
    const float4 hi = hz[i];
    const float ri0 = (hi.x + hi.y) + (hi.z + hi.w);
    const int   yi = Y[i];
    const bool  keep = (c[i] == 0);

    __syncthreads();   // sentinel fill + counter init visible

    // ---- compact i-chunk into class buckets; j suffix histogram ----
    #pragma unroll
    for (int cls = 0; cls < 3; ++cls) {
        const bool mine = keep && (yi == cls);
        const unsigned long long m = __ballot(mine);
        if (m) {                                     // wave-uniform
            const int pop  = (int)__popcll(m);
            const int rank = (int)__popcll(m & ((1ull << lane) - 1ull));
            int base;
            if (lane == 0) base = atomicAdd(&sCnt[cls], pop);
            base = __shfl(base, 0, 64);
            const int slot = base + rank;
            if (mine && slot < CAP) sPad[cls * CAP + slot] = ri0;
        }
        const unsigned long long mj = __ballot(yj > cls);
        if (lane == 0 && mj) atomicAdd(&sSuf[cls], (int)__popcll(mj));
    }
    __syncthreads();

    const float rj0 = (yj > 0) ? rj : -1e30f;
    const float rj1 = (yj > 1) ? rj : -1e30f;
    const float rj2 = (yj > 2) ? rj : -1e30f;

    // ---- pure-VALU pair loop: 4 instr per 64 pairs ----
    float acc = 0.0f;
    #pragma unroll
    for (int cls = 0; cls < 3; ++cls) {
        const float rjc = (cls == 0) ? rj0 : (cls == 1) ? rj1 : rj2;
        const int n = min(sCnt[cls], CAP);
        for (int g = 0; g * 64 < n; ++g) {           // uniform trip count
            float ri = sPad[cls * CAP + g * 64 + lane];
            #pragma unroll
            for (int it = 0; it < 64; ++it) {
                acc += fmaxf(rjc - ri, 0.0f);        // sentinels kill masked terms
                ri = __uint_as_float((unsigned)__builtin_amdgcn_mov_dpp(
                         (int)__float_as_uint(ri), 0x13C /*wave_ror:1*/, 0xF, 0xF, true));
            }
        }
    }

    // ---- block reduction -> one partial (sum + exact count) per block ----
    #pragma unroll
    for (int off = 32; off > 0; off >>= 1) acc += __shfl_down(acc, off, 64);
    if (lane == 0) sA[wave] = acc;
    __syncthreads();
    if (tid == 0) {
        const int gid = blockIdx.y * JT + blockIdx.x;
        const float blockSum = (sA[0] + sA[1]) + (sA[2] + sA[3]);
        const int   blockCnt = sCnt[0] * sSuf[0] + sCnt[1] * sSuf[1] + sCnt[2] * sSuf[2];
        // Relaxed coherent-point stores — NO release (no buffer_wbl2).
        __hip_atomic_store(&psum[gid], blockSum, __ATOMIC_RELAXED, __HIP_MEMORY_SCOPE_AGENT);
        __hip_atomic_store(&pcnt[gid], blockCnt, __ATOMIC_RELAXED, __HIP_MEMORY_SCOPE_AGENT);
        // Wave-local drain: partial stores complete at coherent point BEFORE
        // the ticket add issues. Cheap (no cache maintenance).
        asm volatile("s_waitcnt vmcnt(0)" ::: "memory");
        const int ticket = __hip_atomic_fetch_add(dcnt, 1, __ATOMIC_RELAXED,
                                                  __HIP_MEMORY_SCOPE_AGENT);
        sLast = (ticket == NBLK - 1) ? 1 : 0;
    }
    __syncthreads();

    // ---- last-arriving block reduces the 1024 partials (no spin) ----
    if (sLast) {
        float a = 0.0f; int n = 0;
        #pragma unroll
        for (int k = 0; k < NBLK / BLOCK; ++k) {
            a += __hip_atomic_load(&psum[k * BLOCK + tid], __ATOMIC_RELAXED,
                                   __HIP_MEMORY_SCOPE_AGENT);
            n += __hip_atomic_load(&pcnt[k * BLOCK + tid], __ATOMIC_RELAXED,
                                   __HIP_MEMORY_SCOPE_AGENT);
        }
        #pragma unroll
        for (int off = 32; off > 0; off >>= 1) {
            a += __shfl_down(a, off, 64);
            n += __shfl_down(n, off, 64);
        }
        if (lane == 0) { sA[wave] = a; sN[wave] = n; }
        __syncthreads();   // block-uniform condition: safe
        if (tid == 0) {
            const float A = (sA[0] + sA[1]) + (sA[2] + sA[3]);
            const int   N = (sN[0] + sN[1]) + (sN[2] + sN[3]);
            out[0] = (N > 0) ? (A / (float)N) : 0.0f;
        }
    }
}

extern "C" void kernel_launch(void* const* d_in, const int* in_sizes, int n_in,
                              void* d_out, int out_size, void* d_ws, size_t ws_size,
                              hipStream_t stream) {
    const float4* hz = (const float4*)d_in[0];  // hazards [8192 x 4] f32
    // d_in[1] = S, unused by the reference computation.
    const int* Y = (const int*)d_in[2];
    const int* c = (const int*)d_in[3];

    float* psum = (float*)d_ws;                 // [1024] f32
    int*   pcnt = (int*)d_ws + NBLK;            // [1024] i32
    int*   dcnt = (int*)d_ws + 2 * NBLK;        // [1] ticket counter
    float* out  = (float*)d_out;

    hipMemsetAsync(dcnt, 0, sizeof(int), stream);
    rl_fused<<<dim3(JT, IC), BLOCK, 0, stream>>>(hz, Y, c, psum, pcnt, dcnt, out);
}

// Round 4
// 67.427 us; speedup vs baseline: 1.6215x; 1.1156x over previous
//
#include <hip/hip_runtime.h>

// RankingLoss: loss = sum_{i,j} [c_i==0 && Y_j>Y_i] * relu(risk_j - risk_i) / count
// risk = sum(hazards[:, :4], axis=1). B = 8192, N_CLASSES = 4, MARGIN = 0.
//
// R7 design: back to TWO launches (R0 structure — fusion tested twice and lost:
// coop launch crashed harness; ticket+memset was +7.4us from memset dispatch +
// serialized coherent-point tail). Change vs R0: i-chunk widened 256 -> 512.
//  rl_all (grid 32 j-tiles x 16 i-chunks, 256 thr): each block class-compacts
//    its 512-wide i-chunk in LDS (2 ballot rounds/class, uncensored & Y<3,
//    sentinel-padded to 64), then pure-VALU pair loop: d = rjc - ri;
//    acc += max(d,0); ri = dpp wave_ror:1 (4 instr / 64 pairs). Per-class
//    n ~= 64 (was 32) -> ~25-45% fewer padded pair iterations, half the
//    blocks, half the redundant compaction. Partials -> ws.
//  rl_final: reduce 512 partials, divide.
// Fixed harness floor: 268MB ws re-poison fill ~40us/iter dominates total.

#define B_SIZE 8192
#define BLOCK  256
#define JT     (B_SIZE / BLOCK)      // 32 j-tiles
#define ICH    512                   // i-chunk width
#define IC     (B_SIZE / ICH)        // 16 i-chunks
#define NBLK   (JT * IC)             // 512 partials
#define CAP    128                   // per-class capacity in a 512-chunk (mean 64, sigma 7.5)

__global__ __launch_bounds__(BLOCK) void rl_all(
    const float4* __restrict__ hz,   // hazards [B] as float4 rows
    const int*    __restrict__ Y,
    const int*    __restrict__ c,
    float*        __restrict__ psum,
    int*          __restrict__ pcnt)
{
    __shared__ float sPad[3 * CAP];  // class-bucketed risks, sentinel-padded
    __shared__ int   sCnt[3];        // per-class uncensored count in this i-chunk
    __shared__ int   sSuf[3];        // #{j in tile: yj > a}
    __shared__ float sA[BLOCK / 64];

    const int tid  = threadIdx.x;
    const int lane = tid & 63;
    const int wave = tid >> 6;

    if (tid < 3) { sCnt[tid] = 0; sSuf[tid] = 0; }
    for (int k = tid; k < 3 * CAP; k += BLOCK) sPad[k] = 1e30f;

    // ---- j side: this thread's own column ----
    const int j = blockIdx.x * BLOCK + tid;
    const float4 hj = hz[j];
    const float rj = (hj.x + hj.y) + (hj.z + hj.w);
    const int   yj = Y[j];

    // ---- i side: this thread's TWO rows in the block's 512-wide i-chunk ----
    const int iA = blockIdx.y * ICH + tid;
    const int iB = iA + BLOCK;
    const float4 hA = hz[iA];
    const float4 hB = hz[iB];
    const float rA = (hA.x + hA.y) + (hA.z + hA.w);
    const float rB = (hB.x + hB.y) + (hB.z + hB.w);
    const int   yA = Y[iA];
    const int   yB = Y[iB];
    const bool  kA = (c[iA] == 0);
    const bool  kB = (c[iB] == 0);

    __syncthreads();   // sentinel fill + counter init visible

    // ---- compact i-chunk into class buckets; j suffix histogram ----
    #pragma unroll
    for (int cls = 0; cls < 3; ++cls) {
        {   // sub-row A
            const bool mine = kA && (yA == cls);
            const unsigned long long m = __ballot(mine);
            if (m) {                                 // wave-uniform
                const int pop  = (int)__popcll(m);
                const int rank = (int)__popcll(m & ((1ull << lane) - 1ull));
                int base;
                if (lane == 0) base = atomicAdd(&sCnt[cls], pop);
                base = __shfl(base, 0, 64);
                const int slot = base + rank;
                if (mine && slot < CAP) sPad[cls * CAP + slot] = rA;
            }
        }
        {   // sub-row B
            const bool mine = kB && (yB == cls);
            const unsigned long long m = __ballot(mine);
            if (m) {                                 // wave-uniform
                const int pop  = (int)__popcll(m);
                const int rank = (int)__popcll(m & ((1ull << lane) - 1ull));
                int base;
                if (lane == 0) base = atomicAdd(&sCnt[cls], pop);
                base = __shfl(base, 0, 64);
                const int slot = base + rank;
                if (mine && slot < CAP) sPad[cls * CAP + slot] = rB;
            }
        }
        const unsigned long long mj = __ballot(yj > cls);
        if (lane == 0 && mj) atomicAdd(&sSuf[cls], (int)__popcll(mj));
    }
    __syncthreads();

    const float rj0 = (yj > 0) ? rj : -1e30f;
    const float rj1 = (yj > 1) ? rj : -1e30f;
    const float rj2 = (yj > 2) ? rj : -1e30f;

    // ---- pure-VALU pair loop: 4 instr per 64 pairs ----
    float acc = 0.0f;
    #pragma unroll
    for (int cls = 0; cls < 3; ++cls) {
        const float rjc = (cls == 0) ? rj0 : (cls == 1) ? rj1 : rj2;
        const int n = min(sCnt[cls], CAP);
        for (int g = 0; g * 64 < n; ++g) {           // uniform trip count
            float ri = sPad[cls * CAP + g * 64 + lane];
            #pragma unroll
            for (int it = 0; it < 64; ++it) {
                acc += fmaxf(rjc - ri, 0.0f);        // sentinels kill masked terms
                ri = __uint_as_float((unsigned)__builtin_amdgcn_mov_dpp(
                         (int)__float_as_uint(ri), 0x13C /*wave_ror:1*/, 0xF, 0xF, true));
            }
        }
    }

    // ---- block reduction -> one partial (sum + exact count) per block ----
    #pragma unroll
    for (int off = 32; off > 0; off >>= 1) acc += __shfl_down(acc, off, 64);
    if (lane == 0) sA[wave] = acc;
    __syncthreads();
    if (tid == 0) {
        const int gid = blockIdx.y * JT + blockIdx.x;
        psum[gid] = (sA[0] + sA[1]) + (sA[2] + sA[3]);
        pcnt[gid] = sCnt[0] * sSuf[0] + sCnt[1] * sSuf[1] + sCnt[2] * sSuf[2];
    }
}

__global__ __launch_bounds__(256) void rl_final(
    const float* __restrict__ psum,
    const int*   __restrict__ pcnt,
    float*       __restrict__ out)
{
    const int tid  = threadIdx.x;
    const int lane = tid & 63;
    float a = 0.0f; int n = 0;
    #pragma unroll
    for (int k = 0; k < NBLK / 256; ++k) {
        a += psum[k * 256 + tid];
        n += pcnt[k * 256 + tid];
    }
    #pragma unroll
    for (int off = 32; off > 0; off >>= 1) {
        a += __shfl_down(a, off, 64);
        n += __shfl_down(n, off, 64);
    }
    __shared__ float sa[4];
    __shared__ int   sc[4];
    if (lane == 0) { sa[tid >> 6] = a; sc[tid >> 6] = n; }
    __syncthreads();
    if (tid == 0) {
        const float A = (sa[0] + sa[1]) + (sa[2] + sa[3]);
        const int   N = (sc[0] + sc[1]) + (sc[2] + sc[3]);
        out[0] = (N > 0) ? (A / (float)N) : 0.0f;
    }
}

extern "C" void kernel_launch(void* const* d_in, const int* in_sizes, int n_in,
                              void* d_out, int out_size, void* d_ws, size_t ws_size,
                              hipStream_t stream) {
    const float4* hz = (const float4*)d_in[0];  // hazards [8192 x 4] f32
    // d_in[1] = S, unused by the reference computation.
    const int* Y = (const int*)d_in[2];
    const int* c = (const int*)d_in[3];

    float* psum = (float*)d_ws;                 // [512]
    int*   pcnt = (int*)d_ws + NBLK;            // [512]
    float* out  = (float*)d_out;

    rl_all<<<dim3(JT, IC), BLOCK, 0, stream>>>(hz, Y, c, psum, pcnt);
    rl_final<<<1, 256, 0, stream>>>(psum, pcnt, out);
}